// Round 6
// baseline (98.741 us; speedup 1.0000x reference)
//
#include <hip/hip_runtime.h>
#include <math.h>

// Fused fab_penalty_ls_curve: 13-point stencil over eps + global reduction.
// R5 post-mortem: 92 us; ~50 us overlapped floor. Loads consumed one phase
// (~240 cyc issue) after issue; first-touch HBM latency ~900 cyc > 720 cyc
// of 4-wave cover => ~45% duty, latency-exposed.
// R6: 10-slot row rotation, prefetch TWO phases ahead (slack ~1900 cyc).
// Same RS=32, packed f2 math, frame path — isolates pipeline depth.

typedef float f2 __attribute__((ext_vector_type(2)));
typedef float f4 __attribute__((ext_vector_type(4), aligned(4)));

constexpr float SCF = 1e-12f;
constexpr float EVF = 4.6415888336e-6f;        // 1e-32^(1/6)
constexpr float PID = 2.8559933214452666f;     // pi/1.1
constexpr float PIH = 1.5707963268f;
constexpr int   RS  = 32;                      // rows per strip (even)
constexpr int   FEXTRA = 8;                    // grid.y rows for frame path

struct Row { f4 lo, hi; };                     // cols j-2..j+1, j+2..j+5

__device__ __forceinline__ float C(const Row& r, int k) {
    return k < 4 ? r.lo[k] : r.hi[k - 4];      // k compile-time after unroll
}
__device__ __forceinline__ void load_row(Row& r, const float* p) {
    r.lo = *(const f4*)p;
    r.hi = *(const f4*)(p + 4);
}
__device__ __forceinline__ f2 mk(float a, float b) { f2 v; v.x = a; v.y = b; return v; }
__device__ __forceinline__ f2 fma2(f2 a, f2 b, f2 c) { return __builtin_elementwise_fma(a, b, c); }
__device__ __forceinline__ f2 max2(f2 a, f2 b) { return __builtin_elementwise_max(a, b); }
__device__ __forceinline__ f2 min2(f2 a, f2 b) { return __builtin_elementwise_min(a, b); }
__device__ __forceinline__ f2 abs2(f2 a) { return __builtin_elementwise_abs(a); }
__device__ __forceinline__ f2 rcp2(f2 a) {
    return mk(__builtin_amdgcn_rcpf(a.x), __builtin_amdgcn_rcpf(a.y));
}
__device__ __forceinline__ f2 sqrt2(f2 a) {
    return mk(__builtin_amdgcn_sqrtf(a.x), __builtin_amdgcn_sqrtf(a.y));
}

// ---- packed math for output rows (i, i+1): R0..R5 = rows i-2 .. i+3 ----
__device__ __forceinline__ f2 compute_pair(const Row& R0, const Row& R1,
                                           const Row& R2, const Row& R3,
                                           const Row& R4, const Row& R5,
                                           f2 inv2d, f2 inv4dd) {
    f2 dif[6];                                 // (rp1-rm1) at cols j-1..j+4
    #pragma unroll
    for (int k = 0; k < 6; ++k)
        dif[k] = mk(C(R3, k + 1) - C(R1, k + 1),
                    C(R4, k + 1) - C(R2, k + 1));
    f2 Pz[8];                                  // center rows, cols j-2..j+5
    #pragma unroll
    for (int k = 0; k < 8; ++k)
        Pz[k] = mk(C(R2, k), C(R3, k));

    const f2 sc2 = mk(SCF, SCF);
    f2 part = mk(0.0f, 0.0f);
    #pragma unroll
    for (int q = 0; q < 4; ++q) {
        const f2 c00 = Pz[q + 2];
        const f2 ex  = fma2(dif[q + 1], inv2d, sc2);
        const f2 ey  = fma2(Pz[q + 3] - Pz[q + 1], inv2d, sc2);
        const f2 sxx = mk(C(R4, q + 2) + C(R0, q + 2),
                          C(R5, q + 2) + C(R1, q + 2));
        const f2 exx = (sxx - 2.0f * c00) * inv4dd;
        const f2 eyy = (Pz[q + 4] + Pz[q] - 2.0f * c00) * inv4dd;
        const f2 exy = (dif[q + 2] - dif[q]) * inv4dd;

        const f2 ev  = max2(sqrt2(fma2(ex, ex, ey * ey)), mk(EVF, EVF));
        const f2 num = fma2(ex * ex, eyy,
                       fma2(-2.0f * (ex * ey), exy, (ey * ey) * exx));
        const f2 kabs = abs2(num) * rcp2(ev * ev * ev);

        // |atan(ev/w)| = atan(ev/|w|): min/max range reduction, 1 rcp
        const f2 aw = abs2(c00 + 1e-6f);
        const f2 mx = max2(ev, aw);
        const f2 mn = min2(ev, aw);
        const f2 t  = mn * rcp2(mx);
        const f2 t2 = t * t;
        f2 pl = fma2(t2, mk(-0.01172120f, -0.01172120f), mk(0.05265332f, 0.05265332f));
        pl = fma2(t2, pl, mk(-0.11643287f, -0.11643287f));
        pl = fma2(t2, pl, mk(0.19354346f, 0.19354346f));
        pl = fma2(t2, pl, mk(-0.33262347f, -0.33262347f));
        pl = fma2(t2, pl, mk(0.99997726f, 0.99997726f));
        pl = pl * t;
        f2 at;
        at.x = (ev.x > aw.x) ? PIH - pl.x : pl.x;
        at.y = (ev.y > aw.y) ? PIH - pl.y : pl.y;

        // max(NaN,0)=0 implements nansum
        part = part + max2(fma2(kabs, at, mk(-PID, -PID)), mk(0.0f, 0.0f));
    }
    return part;
}

// ---- frame-path helpers: numpy edge_order=1 gradients on global memory ----
__device__ __forceinline__ float eg(const float* __restrict__ e, int n, int i, int j) {
    return e[(size_t)i * (size_t)n + j];
}
__device__ __forceinline__ float gex(const float* __restrict__ e, int n, int i, int j,
                                     float inv_d, float inv_2d) {
    float v;
    if (i == 0)          v = (eg(e, n, 1, j) - eg(e, n, 0, j)) * inv_d;
    else if (i == n - 1) v = (eg(e, n, n - 1, j) - eg(e, n, n - 2, j)) * inv_d;
    else                 v = (eg(e, n, i + 1, j) - eg(e, n, i - 1, j)) * inv_2d;
    return v + SCF;
}
__device__ __forceinline__ float gey(const float* __restrict__ e, int n, int i, int j,
                                     float inv_d, float inv_2d) {
    float v;
    if (j == 0)          v = (eg(e, n, i, 1) - eg(e, n, i, 0)) * inv_d;
    else if (j == n - 1) v = (eg(e, n, i, n - 1) - eg(e, n, i, n - 2)) * inv_d;
    else                 v = (eg(e, n, i, j + 1) - eg(e, n, i, j - 1)) * inv_2d;
    return v + SCF;
}

__global__ __launch_bounds__(256, 4)
void fab_fused(const float* __restrict__ eps, const float* __restrict__ gs,
               float* __restrict__ out, int n, int G, int nstrip) {
    const float d       = *gs;
    const float inv_2d  = 0.5f / d;
    const float inv_4dd = inv_2d * inv_2d;

    float acc = 0.0f;

    if ((int)blockIdx.y < nstrip) {
        // ================= inner (central-difference) path =================
        const int gg = blockIdx.x * 256 + threadIdx.x;     // col group id
        const bool valid = (gg >= 1) && (gg <= G);
        const int gc = min(max(gg, 1), G);
        const int j  = 4 * gc;                             // cols j..j+3
        const int i0 = 2 + RS * blockIdx.y;
        const int count = min(RS, (n - 2) - i0);           // even by constr.
        const float*  pj = eps + (j - 2);
        const size_t  sn = (size_t)n;
        const f2 inv2d2  = mk(inv_2d, inv_2d);
        const f2 inv4dd2 = mk(inv_4dd, inv_4dd);

        // 10-slot rotation; slot(row r) = (r - (i0-2)) % 10.
        Row s0, s1, s2, s3, s4, s5, s6, s7, s8, s9;
        load_row(s0, pj + (size_t)(i0 - 2) * sn);
        load_row(s1, pj + (size_t)(i0 - 1) * sn);
        load_row(s2, pj + (size_t)(i0    ) * sn);
        load_row(s3, pj + (size_t)(i0 + 1) * sn);
        load_row(s4, pj + (size_t)(i0 + 2) * sn);
        load_row(s5, pj + (size_t)(i0 + 3) * sn);
        load_row(s6, pj + (size_t)(i0 + 4) * sn);
        load_row(s7, pj + (size_t)(i0 + 5) * sn);
        const float* pnext = pj + (size_t)(i0 + 6) * sn;

        f2 acc2 = mk(0.0f, 0.0f);
        // Phase k (k even): compute output rows (i0+k, i0+k+1) from resident
        // rows k-2..k+3; issue loads for rows k+6,k+7 — consumed at phase
        // k+4 (p1/p2 roles) and k+6 (center), i.e. >=2 phases of slack.
        // Load guard: rows needed only up to count+1 -> load iff k+6<=count.
        #define PHASEP(ph, A0, A1, A2, A3, A4, A5, L0, L1)                    \
        {                                                                     \
            const int k = kbase + 2 * (ph);                                   \
            if (k < count) {                                                  \
                if (k + 6 <= count) {                                         \
                    load_row(L0, pnext);                                      \
                    load_row(L1, pnext + sn);                                 \
                }                                                             \
                pnext += 2 * sn;                                              \
                acc2 = acc2 + compute_pair(A0, A1, A2, A3, A4, A5,            \
                                           inv2d2, inv4dd2);                  \
            }                                                                 \
        }

        #pragma unroll 1
        for (int kbase = 0; kbase < RS; kbase += 10) {
            PHASEP(0, s0, s1, s2, s3, s4, s5, s8, s9)
            PHASEP(1, s2, s3, s4, s5, s6, s7, s0, s1)
            PHASEP(2, s4, s5, s6, s7, s8, s9, s2, s3)
            PHASEP(3, s6, s7, s8, s9, s0, s1, s4, s5)
            PHASEP(4, s8, s9, s0, s1, s2, s3, s6, s7)
        }
        #undef PHASEP

        acc = valid ? (acc2.x + acc2.y) : 0.0f;
    } else {
        // ================= frame (edge_order=1 one-sided) path =============
        const float inv_d = inv_2d + inv_2d;
        const int nfr = 4 * n + 8 * (n - 4);
        const int fb  = (int)blockIdx.y - nstrip;                 // 0..FEXTRA-1
        const int tid = (fb * gridDim.x + blockIdx.x) * 256 + threadIdx.x;
        const int nth = FEXTRA * gridDim.x * 256;

        for (int idx = tid; idx < nfr; idx += nth) {
            int i, j;
            if (idx < 4 * n) {
                const int rr = (idx >= n) + (idx >= 2 * n) + (idx >= 3 * n);
                j = idx - rr * n;
                i = (rr < 2) ? rr : (n - 4) + rr;                 // 0,1,n-2,n-1
            } else {
                const int t = idx - 4 * n;
                i = 2 + (t >> 3);                                 // rows 2..n-3
                const int cc = t & 7;
                j = (cc < 4) ? cc : (n - 8) + cc;                 // 0..3, n-4..n-1
            }

            const float ex0 = gex(eps, n, i, j, inv_d, inv_2d);
            const float ey0 = gey(eps, n, i, j, inv_d, inv_2d);

            float exx, exy, eyy;
            if (i == 0)
                exx = (gex(eps, n, 1, j, inv_d, inv_2d) - ex0) * inv_d;
            else if (i == n - 1)
                exx = (ex0 - gex(eps, n, n - 2, j, inv_d, inv_2d)) * inv_d;
            else
                exx = (gex(eps, n, i + 1, j, inv_d, inv_2d)
                     - gex(eps, n, i - 1, j, inv_d, inv_2d)) * inv_2d;

            if (j == 0)
                exy = (gex(eps, n, i, 1, inv_d, inv_2d) - ex0) * inv_d;
            else if (j == n - 1)
                exy = (ex0 - gex(eps, n, i, n - 2, inv_d, inv_2d)) * inv_d;
            else
                exy = (gex(eps, n, i, j + 1, inv_d, inv_2d)
                     - gex(eps, n, i, j - 1, inv_d, inv_2d)) * inv_2d;

            if (j == 0)
                eyy = (gey(eps, n, i, 1, inv_d, inv_2d) - ey0) * inv_d;
            else if (j == n - 1)
                eyy = (ey0 - gey(eps, n, i, n - 2, inv_d, inv_2d)) * inv_d;
            else
                eyy = (gey(eps, n, i, j + 1, inv_d, inv_2d)
                     - gey(eps, n, i, j - 1, inv_d, inv_2d)) * inv_2d;

            const float ev = fmaxf(__builtin_amdgcn_sqrtf(fmaf(ex0, ex0, ey0 * ey0)), EVF);
            const float num = fmaf(ex0 * ex0, eyy,
                              fmaf(-2.0f * ex0 * ey0, exy, ey0 * ey0 * exx));
            const float kabs = fabsf(num) * __builtin_amdgcn_rcpf(ev * ev * ev);

            const float aw = fabsf(eg(eps, n, i, j) + 1e-6f);
            const float mx = fmaxf(ev, aw);
            const float mn = fminf(ev, aw);
            const float t  = mn * __builtin_amdgcn_rcpf(mx);
            const float t2 = t * t;
            float pl = fmaf(t2, -0.01172120f, 0.05265332f);
            pl = fmaf(t2, pl, -0.11643287f);
            pl = fmaf(t2, pl, 0.19354346f);
            pl = fmaf(t2, pl, -0.33262347f);
            pl = fmaf(t2, pl, 0.99997726f);
            pl *= t;
            const float at = (ev > aw) ? (PIH - pl) : pl;

            acc += fmaxf(fmaf(kabs, at, -PID), 0.0f);
        }
    }

    // ---- reduction: wave -> block (LDS) -> one atomic per block ----
    __shared__ float wsum[4];
    #pragma unroll
    for (int off = 32; off; off >>= 1)
        acc += __shfl_down(acc, off, 64);
    if ((threadIdx.x & 63) == 0) wsum[threadIdx.x >> 6] = acc;
    __syncthreads();
    if (threadIdx.x == 0)
        atomicAdd(out, (wsum[0] + wsum[1] + wsum[2] + wsum[3]) * d * d);
}

extern "C" void kernel_launch(void* const* d_in, const int* in_sizes, int n_in,
                              void* d_out, int out_size, void* d_ws, size_t ws_size,
                              hipStream_t stream) {
    const float* eps = (const float*)d_in[0];
    const float* gs  = (const float*)d_in[1];
    float* out = (float*)d_out;

    const long long tot = (long long)in_sizes[0];
    const int n = (int)(sqrt((double)tot) + 0.5);   // 8192

    hipMemsetAsync(out, 0, sizeof(float), stream);

    const int G = (n - 8) / 4;                      // interior col groups
    const int nstrip = (n - 4 + RS - 1) / RS;       // interior rows [2, n-2)

    dim3 block(256, 1);
    dim3 grid(n / 1024, nstrip + FEXTRA);           // last FEXTRA y-rows: frame
    fab_fused<<<grid, block, 0, stream>>>(eps, gs, out, n, G, nstrip);
}

// Round 7
// 92.126 us; speedup vs baseline: 1.0718x; 1.0718x over previous
//
#include <hip/hip_runtime.h>
#include <math.h>

// Fused fab_penalty_ls_curve: 13-point stencil over eps + global reduction.
// R6 post-mortem: 10-slot rotation spilled past the 128-VGPR cap (regressed).
// Revised model: grid quantization dominated all along — 2112 uniform blocks
// vs 1024-block capacity (4/CU at launch_bounds(256,4)) = 3 dispatch rounds
// for 2.06 rounds of work = 69% utilization (also explains R3's 23% occ).
// R7: EXACTLY 1024 blocks (one full round), 64-row strips (row re-read
// 1.19x->1.09x), R5's proven 8-slot depth-1 rotation, frame edge work spread
// 96 el/block inside the same blocks.

typedef float f2 __attribute__((ext_vector_type(2)));
typedef float f4 __attribute__((ext_vector_type(4), aligned(4)));

constexpr float SCF = 1e-12f;
constexpr float EVF = 4.6415888336e-6f;        // 1e-32^(1/6)
constexpr float PID = 2.8559933214452666f;     // pi/1.1
constexpr float PIH = 1.5707963268f;
constexpr int   RS  = 64;                      // rows per strip (mult of 8)

struct Row { f4 lo, hi; };                     // cols j-2..j+1, j+2..j+5

__device__ __forceinline__ float C(const Row& r, int k) {
    return k < 4 ? r.lo[k] : r.hi[k - 4];      // k compile-time after unroll
}
__device__ __forceinline__ void load_row(Row& r, const float* p) {
    r.lo = *(const f4*)p;
    r.hi = *(const f4*)(p + 4);
}
__device__ __forceinline__ f2 mk(float a, float b) { f2 v; v.x = a; v.y = b; return v; }
__device__ __forceinline__ f2 fma2(f2 a, f2 b, f2 c) { return __builtin_elementwise_fma(a, b, c); }
__device__ __forceinline__ f2 max2(f2 a, f2 b) { return __builtin_elementwise_max(a, b); }
__device__ __forceinline__ f2 min2(f2 a, f2 b) { return __builtin_elementwise_min(a, b); }
__device__ __forceinline__ f2 abs2(f2 a) { return __builtin_elementwise_abs(a); }
__device__ __forceinline__ f2 rcp2(f2 a) {
    return mk(__builtin_amdgcn_rcpf(a.x), __builtin_amdgcn_rcpf(a.y));
}
__device__ __forceinline__ f2 sqrt2(f2 a) {
    return mk(__builtin_amdgcn_sqrtf(a.x), __builtin_amdgcn_sqrtf(a.y));
}

// ---- packed math for output rows (i, i+1): R0..R5 = rows i-2 .. i+3 ----
__device__ __forceinline__ f2 compute_pair(const Row& R0, const Row& R1,
                                           const Row& R2, const Row& R3,
                                           const Row& R4, const Row& R5,
                                           f2 inv2d, f2 inv4dd) {
    f2 dif[6];                                 // (rp1-rm1) at cols j-1..j+4
    #pragma unroll
    for (int k = 0; k < 6; ++k)
        dif[k] = mk(C(R3, k + 1) - C(R1, k + 1),
                    C(R4, k + 1) - C(R2, k + 1));
    f2 Pz[8];                                  // center rows, cols j-2..j+5
    #pragma unroll
    for (int k = 0; k < 8; ++k)
        Pz[k] = mk(C(R2, k), C(R3, k));

    const f2 sc2 = mk(SCF, SCF);
    f2 part = mk(0.0f, 0.0f);
    #pragma unroll
    for (int q = 0; q < 4; ++q) {
        const f2 c00 = Pz[q + 2];
        const f2 ex  = fma2(dif[q + 1], inv2d, sc2);
        const f2 ey  = fma2(Pz[q + 3] - Pz[q + 1], inv2d, sc2);
        const f2 sxx = mk(C(R4, q + 2) + C(R0, q + 2),
                          C(R5, q + 2) + C(R1, q + 2));
        const f2 exx = (sxx - 2.0f * c00) * inv4dd;
        const f2 eyy = (Pz[q + 4] + Pz[q] - 2.0f * c00) * inv4dd;
        const f2 exy = (dif[q + 2] - dif[q]) * inv4dd;

        const f2 ev  = max2(sqrt2(fma2(ex, ex, ey * ey)), mk(EVF, EVF));
        const f2 num = fma2(ex * ex, eyy,
                       fma2(-2.0f * (ex * ey), exy, (ey * ey) * exx));
        const f2 kabs = abs2(num) * rcp2(ev * ev * ev);

        // |atan(ev/w)| = atan(ev/|w|): min/max range reduction, 1 rcp
        const f2 aw = abs2(c00 + 1e-6f);
        const f2 mx = max2(ev, aw);
        const f2 mn = min2(ev, aw);
        const f2 t  = mn * rcp2(mx);
        const f2 t2 = t * t;
        f2 pl = fma2(t2, mk(-0.01172120f, -0.01172120f), mk(0.05265332f, 0.05265332f));
        pl = fma2(t2, pl, mk(-0.11643287f, -0.11643287f));
        pl = fma2(t2, pl, mk(0.19354346f, 0.19354346f));
        pl = fma2(t2, pl, mk(-0.33262347f, -0.33262347f));
        pl = fma2(t2, pl, mk(0.99997726f, 0.99997726f));
        pl = pl * t;
        f2 at;
        at.x = (ev.x > aw.x) ? PIH - pl.x : pl.x;
        at.y = (ev.y > aw.y) ? PIH - pl.y : pl.y;

        // max(NaN,0)=0 implements nansum
        part = part + max2(fma2(kabs, at, mk(-PID, -PID)), mk(0.0f, 0.0f));
    }
    return part;
}

// ---- frame-path helpers: numpy edge_order=1 gradients on global memory ----
__device__ __forceinline__ float eg(const float* __restrict__ e, int n, int i, int j) {
    return e[(size_t)i * (size_t)n + j];
}
__device__ __forceinline__ float gex(const float* __restrict__ e, int n, int i, int j,
                                     float inv_d, float inv_2d) {
    float v;
    if (i == 0)          v = (eg(e, n, 1, j) - eg(e, n, 0, j)) * inv_d;
    else if (i == n - 1) v = (eg(e, n, n - 1, j) - eg(e, n, n - 2, j)) * inv_d;
    else                 v = (eg(e, n, i + 1, j) - eg(e, n, i - 1, j)) * inv_2d;
    return v + SCF;
}
__device__ __forceinline__ float gey(const float* __restrict__ e, int n, int i, int j,
                                     float inv_d, float inv_2d) {
    float v;
    if (j == 0)          v = (eg(e, n, i, 1) - eg(e, n, i, 0)) * inv_d;
    else if (j == n - 1) v = (eg(e, n, i, n - 1) - eg(e, n, i, n - 2)) * inv_d;
    else                 v = (eg(e, n, i, j + 1) - eg(e, n, i, j - 1)) * inv_2d;
    return v + SCF;
}

__global__ __launch_bounds__(256, 4)
void fab_fused(const float* __restrict__ eps, const float* __restrict__ gs,
               float* __restrict__ out, int n, int G, int nfr) {
    const float d       = *gs;
    const float inv_2d  = 0.5f / d;
    const float inv_4dd = inv_2d * inv_2d;

    float acc = 0.0f;

    // ========== frame (edge_order=1 one-sided) — 96 elements/block =========
    // Issued first so the scattered loads hide under other waves' compute.
    if (threadIdx.x < 96) {
        const int bflat = blockIdx.y * gridDim.x + blockIdx.x;
        const int idx = bflat * 96 + (int)threadIdx.x;
        if (idx < nfr) {
            const float inv_d = inv_2d + inv_2d;
            int i, j;
            if (idx < 4 * n) {
                const int rr = (idx >= n) + (idx >= 2 * n) + (idx >= 3 * n);
                j = idx - rr * n;
                i = (rr < 2) ? rr : (n - 4) + rr;             // 0,1,n-2,n-1
            } else {
                const int t = idx - 4 * n;
                i = 2 + (t >> 3);                             // rows 2..n-3
                const int cc = t & 7;
                j = (cc < 4) ? cc : (n - 8) + cc;             // 0..3, n-4..n-1
            }

            const float ex0 = gex(eps, n, i, j, inv_d, inv_2d);
            const float ey0 = gey(eps, n, i, j, inv_d, inv_2d);

            float exx, exy, eyy;
            if (i == 0)
                exx = (gex(eps, n, 1, j, inv_d, inv_2d) - ex0) * inv_d;
            else if (i == n - 1)
                exx = (ex0 - gex(eps, n, n - 2, j, inv_d, inv_2d)) * inv_d;
            else
                exx = (gex(eps, n, i + 1, j, inv_d, inv_2d)
                     - gex(eps, n, i - 1, j, inv_d, inv_2d)) * inv_2d;

            if (j == 0)
                exy = (gex(eps, n, i, 1, inv_d, inv_2d) - ex0) * inv_d;
            else if (j == n - 1)
                exy = (ex0 - gex(eps, n, i, n - 2, inv_d, inv_2d)) * inv_d;
            else
                exy = (gex(eps, n, i, j + 1, inv_d, inv_2d)
                     - gex(eps, n, i, j - 1, inv_d, inv_2d)) * inv_2d;

            if (j == 0)
                eyy = (gey(eps, n, i, 1, inv_d, inv_2d) - ey0) * inv_d;
            else if (j == n - 1)
                eyy = (ey0 - gey(eps, n, i, n - 2, inv_d, inv_2d)) * inv_d;
            else
                eyy = (gey(eps, n, i, j + 1, inv_d, inv_2d)
                     - gey(eps, n, i, j - 1, inv_d, inv_2d)) * inv_2d;

            const float ev = fmaxf(__builtin_amdgcn_sqrtf(fmaf(ex0, ex0, ey0 * ey0)), EVF);
            const float num = fmaf(ex0 * ex0, eyy,
                              fmaf(-2.0f * ex0 * ey0, exy, ey0 * ey0 * exx));
            const float kabs = fabsf(num) * __builtin_amdgcn_rcpf(ev * ev * ev);

            const float aw = fabsf(eg(eps, n, i, j) + 1e-6f);
            const float mx = fmaxf(ev, aw);
            const float mn = fminf(ev, aw);
            const float t  = mn * __builtin_amdgcn_rcpf(mx);
            const float t2 = t * t;
            float pl = fmaf(t2, -0.01172120f, 0.05265332f);
            pl = fmaf(t2, pl, -0.11643287f);
            pl = fmaf(t2, pl, 0.19354346f);
            pl = fmaf(t2, pl, -0.33262347f);
            pl = fmaf(t2, pl, 0.99997726f);
            pl *= t;
            const float at = (ev > aw) ? (PIH - pl) : pl;

            acc += fmaxf(fmaf(kabs, at, -PID), 0.0f);
        }
    }

    // ================= inner (central-difference) strip ====================
    {
        const int gg = blockIdx.x * 256 + threadIdx.x;     // col group id
        const bool valid = (gg >= 1) && (gg <= G);
        const int gc = min(max(gg, 1), G);
        const int j  = 4 * gc;                             // cols j..j+3
        const int i0 = 2 + RS * blockIdx.y;
        const int count = min(RS, (n - 2) - i0);           // even by constr.
        const float*  pj = eps + (j - 2);
        const size_t  sn = (size_t)n;
        const f2 inv2d2  = mk(inv_2d, inv_2d);
        const f2 inv4dd2 = mk(inv_4dd, inv_4dd);

        Row s0, s1, s2, s3, s4, s5, s6, s7;
        load_row(s0, pj + (size_t)(i0 - 2) * sn);
        load_row(s1, pj + (size_t)(i0 - 1) * sn);
        load_row(s2, pj + (size_t)(i0    ) * sn);
        load_row(s3, pj + (size_t)(i0 + 1) * sn);
        load_row(s4, pj + (size_t)(i0 + 2) * sn);
        load_row(s5, pj + (size_t)(i0 + 3) * sn);
        const float* pnext = pj + (size_t)(i0 + 4) * sn;

        f2 acc2 = mk(0.0f, 0.0f);
        // phase: compute output rows (i0+k, i0+k+1) from 6 resident rows,
        // prefetch rows i0+k+4, i0+k+5 (consumed next phase).
        #define PHASEP(ph, A0, A1, A2, A3, A4, A5, L0, L1)                    \
        {                                                                     \
            const int k = kbase + 2 * (ph);                                   \
            if (k < count) {                                                  \
                if (k + 2 < count) {                                          \
                    load_row(L0, pnext);                                      \
                    load_row(L1, pnext + sn);                                 \
                }                                                             \
                pnext += 2 * sn;                                              \
                acc2 = acc2 + compute_pair(A0, A1, A2, A3, A4, A5,            \
                                           inv2d2, inv4dd2);                  \
            }                                                                 \
        }

        #pragma unroll 1
        for (int kbase = 0; kbase < RS; kbase += 8) {
            PHASEP(0, s0, s1, s2, s3, s4, s5, s6, s7)
            PHASEP(1, s2, s3, s4, s5, s6, s7, s0, s1)
            PHASEP(2, s4, s5, s6, s7, s0, s1, s2, s3)
            PHASEP(3, s6, s7, s0, s1, s2, s3, s4, s5)
        }
        #undef PHASEP

        if (valid) acc += acc2.x + acc2.y;
    }

    // ---- reduction: wave -> block (LDS) -> one atomic per block ----
    __shared__ float wsum[4];
    #pragma unroll
    for (int off = 32; off; off >>= 1)
        acc += __shfl_down(acc, off, 64);
    if ((threadIdx.x & 63) == 0) wsum[threadIdx.x >> 6] = acc;
    __syncthreads();
    if (threadIdx.x == 0)
        atomicAdd(out, (wsum[0] + wsum[1] + wsum[2] + wsum[3]) * d * d);
}

extern "C" void kernel_launch(void* const* d_in, const int* in_sizes, int n_in,
                              void* d_out, int out_size, void* d_ws, size_t ws_size,
                              hipStream_t stream) {
    const float* eps = (const float*)d_in[0];
    const float* gs  = (const float*)d_in[1];
    float* out = (float*)d_out;

    const long long tot = (long long)in_sizes[0];
    const int n = (int)(sqrt((double)tot) + 0.5);   // 8192

    hipMemsetAsync(out, 0, sizeof(float), stream);

    const int G = (n - 8) / 4;                      // interior col groups
    const int nstrip = (n - 4 + RS - 1) / RS;       // interior rows [2, n-2): 128
    const int nfr = 4 * n + 8 * (n - 4);            // frame element count

    dim3 block(256, 1);
    dim3 grid(n / 1024, nstrip);                    // 8 x 128 = 1024 = capacity
    fab_fused<<<grid, block, 0, stream>>>(eps, gs, out, n, G, nfr);
}